// Round 13
// baseline (22.919 us; speedup 1.0000x reference)
//
#include <hip/hip_runtime.h>
#include <math.h>

#define BB 32
#define LL 512
#define HH 352
#define WW 1216
#define NLINES (BB * LL)          // 16384
#define LPW 2                     // lines per wave
#define NBLK2 (NLINES / (LPW * 4))  // 2048 blocks, 4 waves each

__device__ __forceinline__ float line_degree(int x0, int y0, int x1, int y1) {
    // Replicates: slopes = |(y1f - y0f) / (x1f - x0f + 1e-6)|
    //             degrees = (arctan(slopes) * 180.0 / pi) % 90.0
    float slope = fabsf(((float)y1 - (float)y0) / ((float)x1 - (float)x0 + 1e-6f));
    float deg = (atanf(slope) * 180.0f) / 3.14159274101257324f;  // f32(pi)
    return fmodf(deg, 90.0f);
}

struct Ctx {
    int off0, A, Bm, tdm;
    int dmaj;       // true major length
    int dwalk;      // dmaj if active else 0 (degenerates loads to broadcast)
    unsigned den, M;
    int ep0, ep1;   // endpoint offsets
};

__device__ __forceinline__ Ctx make_ctx(int4 ln) {
    Ctx c;
    int x0 = min(max(ln.x, 0), WW - 1);
    int y0 = min(max(ln.y, 0), HH - 1);
    int x1 = min(max(ln.z, 0), WW - 1);
    int y1 = min(max(ln.w, 0), HH - 1);
    int dx = abs(x1 - x0), dy = abs(y1 - y0);
    bool xm = dx > dy;
    c.dmaj = xm ? dx : dy;
    int dmin = xm ? dy : dx;
    int sx = (x1 > x0) - (x1 < x0);
    int sy = (y1 > y0) - (y1 < y0);
    int smaj = xm ? sx : sy;
    int smin = xm ? sy : sx;
    int maj0 = xm ? x0 : y0;
    int min0 = xm ? y0 : x0;
    int sA = xm ? 1 : WW;
    int sB = xm ? WW : 1;
    c.A = smaj * sA;
    c.Bm = smin * sB;
    c.off0 = maj0 * sA + min0 * sB;
    c.tdm = 2 * dmin;
    c.den = (unsigned)max(2 * c.dmaj, 2);
    // Wave-uniform magic reciprocal: exact floor(num/den) for num < 2^22.
    c.M = 0xFFFFFFFFu / c.den + 1u;
    c.ep0 = y0 * WW + x0;
    c.ep1 = y1 * WW + x1;
    c.dwalk = 0;
    return c;
}

__device__ __forceinline__ int path_off(const Ctx& c, int idx) {
    int idc = min(idx, c.dwalk);     // clamp: padding repeats endpoint
    unsigned num = (unsigned)(c.tdm * idc) + (unsigned)c.dmaj;
    unsigned q = __umulhi(num, c.M);
    q -= (q * c.den > num) ? 1u : 0u;
    return c.off0 + idc * c.A + (int)q * c.Bm;
}

// Unweighted diff-sums, 2 lines per wave; A and B gather rounds merged so
// their memory-latency rounds overlap (16 loads in flight per round).
__global__ void __launch_bounds__(256) line_walk_kernel(
        const float* __restrict__ pred, const int* __restrict__ lines,
        float* __restrict__ partials, unsigned* __restrict__ counter) {
    if (blockIdx.x == 0 && threadIdx.x == 0) *counter = 0;  // reset for finalize
    int lane = threadIdx.x & 63;
    int w = threadIdx.x >> 6;
    // XCD-aware swizzle: each XCD gets a contiguous chunk of lines.
    int bid = blockIdx.x;
    int swz = (bid & 7) * (NBLK2 / 8) + (bid >> 3);
    int W = swz * 4 + w;                 // wave id
    int g0 = W * LPW, g1 = g0 + 1;
    int b = g0 >> 9;                     // both lines in same batch (LL even)

    int4 lA = ((const int4*)lines)[g0];
    int4 lB = ((const int4*)lines)[g1];
    Ctx cA = make_ctx(lA);
    Ctx cB = make_ctx(lB);

    const float* __restrict__ p = pred + (size_t)b * (HH * WW);

    // All 4 endpoint loads issue together (one latency round for both lines).
    float vfA = p[cA.ep0];
    float vlA = p[cA.ep1];
    float vfB = p[cB.ep0];
    float vlB = p[cB.ep1];

    // Early-out: reference zeroes diff_sums when |vf - vl| < 0.5 (~28%).
    bool actA = (fabsf(vfA - vlA) >= 0.5f) && (cA.dmaj > 0);
    bool actB = (fabsf(vfB - vlB) >= 0.5f) && (cB.dmaj > 0);
    cA.dwalk = actA ? cA.dmaj : 0;   // inactive -> all slots broadcast off0
    cB.dwalk = actB ? cB.dmaj : 0;

    // Rounds: batch-8 of 63-point chunks per line; merged across lines.
    int nbA = actA ? ((cA.dmaj + 62) / 63 + 7) >> 3 : 0;
    int nbB = actB ? ((cB.dmaj + 62) / 63 + 7) >> 3 : 0;
    int rounds = max(nbA, nbB);

    float s0 = 0.0f, s1 = 0.0f;
    int idx = lane;
    for (int t = 0; t < rounds; ++t, idx += 504) {
        int offsA[8], offsB[8];
        #pragma unroll
        for (int k = 0; k < 8; ++k) {
            offsA[k] = path_off(cA, idx + 63 * k);
            offsB[k] = path_off(cB, idx + 63 * k);
        }
        float vA[8], vB[8];
        #pragma unroll
        for (int k = 0; k < 8; ++k) vA[k] = p[offsA[k]];
        #pragma unroll
        for (int k = 0; k < 8; ++k) vB[k] = p[offsB[k]];
        #pragma unroll
        for (int k = 0; k < 8; ++k) {
            float nA = __shfl_down(vA[k], 1);
            float nB = __shfl_down(vB[k], 1);
            float dA = fabsf(nA - vA[k]);
            float dB = fabsf(nB - vB[k]);
            if (lane < 63) { s0 += dA; s1 += dB; }
        }
    }
    // Two interleaved wave reductions (dependency chains overlap).
    #pragma unroll
    for (int off = 32; off > 0; off >>= 1) {
        s0 += __shfl_down(s0, off);
        s1 += __shfl_down(s1, off);
    }
    if (lane == 0) {
        partials[g0] = actA ? s0 : 0.0f;
        partials[g1] = actB ? s1 : 0.0f;
    }
}

// Degree + per-batch max + weight + weighted block-sum; last block writes out.
// powf chains strength-reduced: d^1.5 = d*sqrt(d); (t^2.5)^0.4 = t;
// x^4 = sq(sq(x)). Deviation vs libm powf ~1e-5 relative (threshold 112).
__global__ void finalize_kernel(const int* __restrict__ lines,
                                const float* __restrict__ partials,
                                float* __restrict__ bsum,
                                unsigned* __restrict__ counter,
                                float* __restrict__ out) {
    __shared__ float red[LL];
    int b = blockIdx.x;
    int t = threadIdx.x;
    int g = b * LL + t;
    int4 ln = ((const int4*)lines)[g];
    int x0 = min(max(ln.x, 0), WW - 1);
    int y0 = min(max(ln.y, 0), HH - 1);
    int x1 = min(max(ln.z, 0), WW - 1);
    int y1 = min(max(ln.w, 0), HH - 1);
    float deg = line_degree(x0, y0, x1, y1);
    red[t] = deg;
    __syncthreads();
    for (int s = LL / 2; s > 0; s >>= 1) {
        if (t < s) red[t] = fmaxf(red[t], red[t + s]);
        __syncthreads();
    }
    float mxv = red[0];
    __syncthreads();
    float skewed = (deg * sqrtf(deg)) / sqrtf(mxv + 1.0f);
    float tt = fabsf(skewed - 45.0f);
    float h = 90.0f - tt;                    // == 90 - (tt^2.5)^0.4
    float hw = h * (1.0f / 300.0f);
    float hw2 = hw * hw;
    float wgt = hw2 * hw2;                   // (h/300)^4
    red[t] = wgt * partials[g];
    __syncthreads();
    for (int s = LL / 2; s > 0; s >>= 1) {
        if (t < s) red[t] += red[t + s];
        __syncthreads();
    }
    if (t == 0) {
        bsum[b] = red[0];
        __threadfence();                     // release bsum before counter bump
        if (atomicAdd(counter, 1u) == BB - 1) {
            __threadfence();                 // acquire others' bsum
            float tot = 0.0f;
            #pragma unroll
            for (int i = 0; i < BB; ++i) tot += bsum[i];  // fixed order: deterministic
            out[0] = tot;
        }
    }
}

extern "C" void kernel_launch(void* const* d_in, const int* in_sizes, int n_in,
                              void* d_out, int out_size, void* d_ws, size_t ws_size,
                              hipStream_t stream) {
    const float* pred = (const float*)d_in[0];
    const int* lines = (const int*)d_in[1];
    float* out = (float*)d_out;
    float* ws = (float*)d_ws;
    float* partials = ws;                    // 16384 floats
    float* bsum = ws + NLINES;               // 32 floats
    unsigned* counter = (unsigned*)(ws + NLINES + BB);  // 1 uint

    line_walk_kernel<<<NBLK2, 256, 0, stream>>>(pred, lines, partials, counter);
    finalize_kernel<<<BB, LL, 0, stream>>>(lines, partials, bsum, counter, out);
}